// Round 5
// baseline (288.450 us; speedup 1.0000x reference)
//
#include <hip/hip_runtime.h>
#include <hip/hip_bf16.h>
#include <stdint.h>

// GRUModel: y[t,b,:] = GRUCell(x[t,b,:], hid[t,b,:]) per (t,b). M = T*B = 131072, H = I = 128.
//
// v4: latency-serialization fixes on the v3.1 LDS-staged structure.
//   - 256-thread blocks (4 waves), 2 column-classes: block cls=bid&1 handles hcols cls*64..+63.
//     Finer residency quantization (3-4 blocks/CU vs 1x8-wave), 4-wave barriers, cross-block overlap.
//     x/hid logically read 2x but L3-served (round-4 evidence: dur was FETCH-independent).
//   - Prefetch issued AFTER __syncthreads: the barrier's implicit vmcnt(0) no longer drains the
//     fresh t+1 loads (v3.1 exposed full memory latency at every barrier). One barrier per tile.
//   - Epilogue divisions -> __builtin_amdgcn_rcpf (no -ffast-math: 1/(1+e) was compiling to the
//     ~12-instr precise-div sequence x12 per lane-tile, sitting on the serial inter-barrier path).
//   - Everything else (weight fragments in VGPR, swizzled bf16 LDS tiles, cvt-once staging,
//     hout from stager regs, f32x4 epilogue stores) unchanged from the verified v3.1.

typedef __attribute__((ext_vector_type(8))) short short8;    // 8 bf16 = 4 VGPRs
typedef __attribute__((ext_vector_type(4))) short short4v;   // 4 bf16 = 2 VGPRs
typedef __attribute__((ext_vector_type(4))) float f32x4;

__device__ __forceinline__ float rcpf(float v) { return __builtin_amdgcn_rcpf(v); }
__device__ __forceinline__ float fast_sigmoid(float v) {
    return rcpf(1.0f + __expf(-v));
}
__device__ __forceinline__ float fast_tanh(float v) {
    return 2.0f * rcpf(1.0f + __expf(-2.0f * v)) - 1.0f;  // inf-safe
}

// fp32 -> bf16 (RNE) via HW cvt; compiler packs pairs into v_cvt_pk_bf16_f32
__device__ __forceinline__ short f2bf(float f) {
    union { __hip_bfloat16 b; short s; } u; u.b = __float2bfloat16(f);
    return u.s;
}
__device__ __forceinline__ short8 pack8(f32x4 a, f32x4 b) {
    short8 r;
    r[0] = f2bf(a[0]); r[1] = f2bf(a[1]); r[2] = f2bf(a[2]); r[3] = f2bf(a[3]);
    r[4] = f2bf(b[0]); r[5] = f2bf(b[1]); r[6] = f2bf(b[2]); r[7] = f2bf(b[3]);
    return r;
}
__device__ __forceinline__ short4v cvt4(f32x4 a) {
    short4v r;
    r[0] = f2bf(a[0]); r[1] = f2bf(a[1]); r[2] = f2bf(a[2]); r[3] = f2bf(a[3]);
    return r;
}

__global__ __launch_bounds__(256) void gru_kernel(
    const float* __restrict__ x,
    const float* __restrict__ hid,
    const float* __restrict__ Wih,
    const float* __restrict__ Whh,
    const float* __restrict__ bih,
    const float* __restrict__ bhh,
    float* __restrict__ y,
    float* __restrict__ hout,
    int ntiles, int tpb)
{
    // [buf][ x:0..4095 | hid:4096..8191 ] bf16, 16 rows x 256B, swizzle byte^((row&7)<<4)
    __shared__ __align__(16) char lds[2 * 8192];

    const int tid  = threadIdx.x;
    const int lane = tid & 63;
    const int w    = tid >> 6;       // wave 0..3
    const int l15  = lane & 15;
    const int q    = lane >> 4;      // quad 0..3

    const int cls = blockIdx.x & 1;          // column class: hcols cls*64 .. cls*64+63
    const int grp = blockIdx.x >> 1;         // tile group

    // ---- weights -> VGPR A-fragments (one-time; wave w owns hcols cls*64 + w*16 .. +15) ----
    // A-frag for 16x16x32: lane l15 = m (h-subcol), holds k = s*32 + q*8 .. +7  (verified v2-v3.1)
    short8 wf[6][4];                 // g = {i_r,i_z,i_n,h_r,h_z,h_n}
    #pragma unroll
    for (int g = 0; g < 6; ++g) {
        const float* Wp  = (g < 3) ? Wih : Whh;
        const float* src = Wp + (size_t)((g % 3) * 128 + cls * 64 + w * 16 + l15) * 128 + q * 8;
        #pragma unroll
        for (int s = 0; s < 4; ++s) {
            f32x4 a = *(const f32x4*)(src + s * 32);
            f32x4 b = *(const f32x4*)(src + s * 32 + 4);
            wf[g][s] = pack8(a, b);
        }
    }

    // ---- per-lane biases for this lane's 4 h-cols ----
    const int h0 = cls * 64 + w * 16 + q * 4;
    f32x4 br4  = *(const f32x4*)(bih + h0)       + *(const f32x4*)(bhh + h0);
    f32x4 bz4  = *(const f32x4*)(bih + 128 + h0) + *(const f32x4*)(bhh + 128 + h0);
    f32x4 bin4 = *(const f32x4*)(bih + 256 + h0);
    f32x4 bhn4 = *(const f32x4*)(bhh + 256 + h0);

    // ---- tile range ----
    const int t0 = grp * tpb;
    const int t1 = (t0 + tpb < ntiles) ? (t0 + tpb) : ntiles;
    if (t0 >= t1) return;

    // ---- staging: waves 0-1 stage x, waves 2-3 stage hid; 64B fp32 per lane per tile ----
    const int    opnd = w >> 1;                         // 0 = x, 1 = hid
    const int    srow = (w & 1) * 8 + (lane >> 3);      // tile row 0..15
    const int    scol = (lane & 7) * 16;                // float col 0,16,..,112
    const float* gsrc = opnd ? hid : x;
    const float* gp   = gsrc + (size_t)(t0 * 16 + srow) * 128 + scol;

    const int dbase = opnd * 4096 + srow * 256;
    const int sz    = (srow & 7) << 4;
    const int dst0  = dbase + (((lane & 7) * 32 +  0) ^ sz);
    const int dst1  = dbase + (((lane & 7) * 32 +  8) ^ sz);
    const int dst2  = dbase + (((lane & 7) * 32 + 16) ^ sz);
    const int dst3  = dbase + (((lane & 7) * 32 + 24) ^ sz);

    // fragment read offsets (swizzle matches write side; pattern verified conflict-negligible r4)
    int xoff[4];
    #pragma unroll
    for (int s = 0; s < 4; ++s)
        xoff[s] = l15 * 256 + ((s * 64 + q * 16) ^ ((l15 & 7) << 4));

    const float* hvp = hid  + (size_t)(t0 * 16 + l15) * 128 + h0;
    float*       yp  = y    + (size_t)(t0 * 16 + l15) * 128 + h0;
    float*       op  = hout + (size_t)(t0 * 16 + srow) * 128 + scol;
    const bool do_hout = (cls == 0) && (opnd == 1);     // wave-uniform

    // ---- prologue: load tile t0's stage data ----
    f32x4 s0 = *(const f32x4*)(gp);
    f32x4 s1 = *(const f32x4*)(gp + 4);
    f32x4 s2 = *(const f32x4*)(gp + 8);
    f32x4 s3 = *(const f32x4*)(gp + 12);

    for (int t = t0; t < t1; ++t) {
        char* lb = lds + ((t & 1) << 13);

        // -- stage tile t (cvt-once, swizzled 8B writes); waits only t's own loads --
        *(short4v*)(lb + dst0) = cvt4(s0);
        *(short4v*)(lb + dst1) = cvt4(s1);
        *(short4v*)(lb + dst2) = cvt4(s2);
        *(short4v*)(lb + dst3) = cvt4(s3);
        __syncthreads();   // drain is cheap: all prior vmem already consumed/completed

        // -- post-barrier: hout from regs, then prefetch t+1 (overwrites s0..s3) --
        if (do_hout) {
            *(f32x4*)(op)      = s0;
            *(f32x4*)(op + 4)  = s1;
            *(f32x4*)(op + 8)  = s2;
            *(f32x4*)(op + 12) = s3;
            op += 2048;
        }
        if (t + 1 < t1) {
            gp += 2048;
            s0 = *(const f32x4*)(gp);
            s1 = *(const f32x4*)(gp + 4);
            s2 = *(const f32x4*)(gp + 8);
            s3 = *(const f32x4*)(gp + 12);
        }

        // -- compute tile t --
        f32x4 hv = *(const f32x4*)hvp;                  // L1-hit (just staged by this block)
        short8 xa[4], ha[4];
        #pragma unroll
        for (int s = 0; s < 4; ++s) {
            xa[s] = *(const short8*)(lb + xoff[s]);
            ha[s] = *(const short8*)(lb + xoff[s] + 4096);
        }
        f32x4 acc[6];
        #pragma unroll
        for (int g = 0; g < 6; ++g) acc[g] = (f32x4){0.f, 0.f, 0.f, 0.f};
        #pragma unroll
        for (int s = 0; s < 4; ++s) {
            #pragma unroll
            for (int g = 0; g < 6; ++g) {
                acc[g] = __builtin_amdgcn_mfma_f32_16x16x32_bf16(
                    wf[g][s], (g < 3) ? xa[s] : ha[s], acc[g], 0, 0, 0);
            }
        }

        // -- epilogue: lane = batch row l15, h-cols h0..h0+3 (r = reg idx) --
        f32x4 yv;
        #pragma unroll
        for (int r = 0; r < 4; ++r) {
            float rv = fast_sigmoid(acc[0][r] + acc[3][r] + br4[r]);
            float zv = fast_sigmoid(acc[1][r] + acc[4][r] + bz4[r]);
            float nv = fast_tanh(acc[2][r] + bin4[r] + rv * (acc[5][r] + bhn4[r]));
            yv[r] = (1.0f - zv) * nv + zv * hv[r];
        }
        *(f32x4*)yp = yv;
        hvp += 2048; yp += 2048;
    }
}

extern "C" void kernel_launch(void* const* d_in, const int* in_sizes, int n_in,
                              void* d_out, int out_size, void* d_ws, size_t ws_size,
                              hipStream_t stream) {
    const float* x   = (const float*)d_in[0];
    const float* hid = (const float*)d_in[1];
    const float* Wih = (const float*)d_in[2];
    const float* Whh = (const float*)d_in[3];
    const float* bih = (const float*)d_in[4];
    const float* bhh = (const float*)d_in[5];

    const int M = in_sizes[0] / 128;               // T*B = 131072
    float* y    = (float*)d_out;
    float* hout = y + (size_t)M * 128;

    const int ntiles = M / 16;                     // 8192 row-tiles
    int ngroups = 1024;
    if (ngroups > ntiles) ngroups = ntiles;
    const int tpb  = (ntiles + ngroups - 1) / ngroups;   // 8 tiles/block at M=131072
    const int grid = 2 * ngroups;                        // x2 column classes

    gru_kernel<<<grid, 256, 0, stream>>>(x, hid, Wih, Whh, bih, bhh, y, hout, ntiles, tpb);
}

// Round 6
// 286.218 us; speedup vs baseline: 1.0078x; 1.0078x over previous
//
#include <hip/hip_runtime.h>
#include <hip/hip_bf16.h>
#include <stdint.h>

// GRUModel: y[t,b,:] = GRUCell(x[t,b,:], hid[t,b,:]) per (t,b). M = T*B = 131072, H = I = 128.
//
// v6: round-5 structure + T4 (counted-vmcnt discipline): the ONLY structural change is the
// barrier. __syncthreads() emits s_waitcnt vmcnt(0) -> every tile drained the y/hout stores
// and the fresh prefetch (the m97 drain; ~60% idle in r4/r5 counters). Replaced with
// s_waitcnt lgkmcnt(0) + raw s_barrier: LDS handoff stays correct (lgkm drained before
// signaling), while vmem stores/loads legally cross the barrier (stores are never read back;
// prefetch loads are same-wave-consumed). Prefetch moves back BEFORE the barrier -> full-tile
// latency cover. Stage loads issued before the weight prologue (HBM path starts at cycle 0).
//
// Carried from r5 (verified): 256-thr blocks, cls-split (64 h-cols), weights-as-A resident in
// VGPRs, cvt-once swizzled bf16 LDS (2x8KB dbuf), hout from stager regs, rcpf gates, f32x4 I/O.

typedef __attribute__((ext_vector_type(8))) short short8;    // 8 bf16 = 4 VGPRs
typedef __attribute__((ext_vector_type(4))) short short4v;   // 4 bf16 = 2 VGPRs
typedef __attribute__((ext_vector_type(4))) float f32x4;

// LDS-only barrier: drain LDS ops, let vmem (stores + prefetch loads) stay in flight.
#define LDS_BARRIER() do {                                   \
    asm volatile("s_waitcnt lgkmcnt(0)" ::: "memory");       \
    __builtin_amdgcn_s_barrier();                            \
    asm volatile("" ::: "memory");                           \
} while (0)

__device__ __forceinline__ float rcpf(float v) { return __builtin_amdgcn_rcpf(v); }
__device__ __forceinline__ float fast_sigmoid(float v) {
    return rcpf(1.0f + __expf(-v));
}
__device__ __forceinline__ float fast_tanh(float v) {
    return 2.0f * rcpf(1.0f + __expf(-2.0f * v)) - 1.0f;  // inf-safe
}

// fp32 -> bf16 (RNE) via HW cvt; compiler packs pairs into v_cvt_pk_bf16_f32
__device__ __forceinline__ short f2bf(float f) {
    union { __hip_bfloat16 b; short s; } u; u.b = __float2bfloat16(f);
    return u.s;
}
__device__ __forceinline__ short8 pack8(f32x4 a, f32x4 b) {
    short8 r;
    r[0] = f2bf(a[0]); r[1] = f2bf(a[1]); r[2] = f2bf(a[2]); r[3] = f2bf(a[3]);
    r[4] = f2bf(b[0]); r[5] = f2bf(b[1]); r[6] = f2bf(b[2]); r[7] = f2bf(b[3]);
    return r;
}
__device__ __forceinline__ short4v cvt4(f32x4 a) {
    short4v r;
    r[0] = f2bf(a[0]); r[1] = f2bf(a[1]); r[2] = f2bf(a[2]); r[3] = f2bf(a[3]);
    return r;
}

__global__ __launch_bounds__(256) void gru_kernel(
    const float* __restrict__ x,
    const float* __restrict__ hid,
    const float* __restrict__ Wih,
    const float* __restrict__ Whh,
    const float* __restrict__ bih,
    const float* __restrict__ bhh,
    float* __restrict__ y,
    float* __restrict__ hout,
    int ntiles, int tpb)
{
    // [buf][ x:0..4095 | hid:4096..8191 ] bf16, 16 rows x 256B, swizzle byte^((row&7)<<4)
    __shared__ __align__(16) char lds[2 * 8192];

    const int tid  = threadIdx.x;
    const int lane = tid & 63;
    const int w    = tid >> 6;       // wave 0..3
    const int l15  = lane & 15;
    const int q    = lane >> 4;      // quad 0..3

    const int cls = blockIdx.x & 1;          // column class: hcols cls*64 .. cls*64+63
    const int grp = blockIdx.x >> 1;         // tile group

    // ---- tile range ----
    const int t0 = grp * tpb;
    const int t1 = (t0 + tpb < ntiles) ? (t0 + tpb) : ntiles;
    if (t0 >= t1) return;

    // ---- staging geometry: waves 0-1 stage x, waves 2-3 stage hid; 64B fp32/lane/tile ----
    const int    opnd = w >> 1;                         // 0 = x, 1 = hid
    const int    srow = (w & 1) * 8 + (lane >> 3);      // tile row 0..15
    const int    scol = (lane & 7) * 16;                // float col 0,16,..,112
    const float* gsrc = opnd ? hid : x;
    const float* gp   = gsrc + (size_t)(t0 * 16 + srow) * 128 + scol;

    // ---- issue tile t0's stage loads FIRST (HBM critical path starts now) ----
    f32x4 s0 = *(const f32x4*)(gp);
    f32x4 s1 = *(const f32x4*)(gp + 4);
    f32x4 s2 = *(const f32x4*)(gp + 8);
    f32x4 s3 = *(const f32x4*)(gp + 12);

    // ---- weights -> VGPR A-fragments (one-time; wave w owns hcols cls*64 + w*16 .. +15) ----
    // A-frag for 16x16x32: lane l15 = m (h-subcol), holds k = s*32 + q*8 .. +7  (verified v2+)
    short8 wf[6][4];                 // g = {i_r,i_z,i_n,h_r,h_z,h_n}
    #pragma unroll
    for (int g = 0; g < 6; ++g) {
        const float* Wp  = (g < 3) ? Wih : Whh;
        const float* src = Wp + (size_t)((g % 3) * 128 + cls * 64 + w * 16 + l15) * 128 + q * 8;
        #pragma unroll
        for (int s = 0; s < 4; ++s) {
            f32x4 a = *(const f32x4*)(src + s * 32);
            f32x4 b = *(const f32x4*)(src + s * 32 + 4);
            wf[g][s] = pack8(a, b);
        }
    }

    // ---- per-lane biases for this lane's 4 h-cols ----
    const int h0 = cls * 64 + w * 16 + q * 4;
    f32x4 br4  = *(const f32x4*)(bih + h0)       + *(const f32x4*)(bhh + h0);
    f32x4 bz4  = *(const f32x4*)(bih + 128 + h0) + *(const f32x4*)(bhh + 128 + h0);
    f32x4 bin4 = *(const f32x4*)(bih + 256 + h0);
    f32x4 bhn4 = *(const f32x4*)(bhh + 256 + h0);

    // ---- LDS addresses ----
    const int dbase = opnd * 4096 + srow * 256;
    const int sz    = (srow & 7) << 4;
    const int dst0  = dbase + (((lane & 7) * 32 +  0) ^ sz);
    const int dst1  = dbase + (((lane & 7) * 32 +  8) ^ sz);
    const int dst2  = dbase + (((lane & 7) * 32 + 16) ^ sz);
    const int dst3  = dbase + (((lane & 7) * 32 + 24) ^ sz);

    // fragment read offsets (swizzle matches write side)
    int xoff[4];
    #pragma unroll
    for (int s = 0; s < 4; ++s)
        xoff[s] = l15 * 256 + ((s * 64 + q * 16) ^ ((l15 & 7) << 4));

    const float* hvp = hid  + (size_t)(t0 * 16 + l15) * 128 + h0;
    float*       yp  = y    + (size_t)(t0 * 16 + l15) * 128 + h0;
    float*       op  = hout + (size_t)(t0 * 16 + srow) * 128 + scol;
    const bool do_hout = (cls == 0) && (opnd == 1);     // wave-uniform

    for (int t = t0; t < t1; ++t) {
        char* lb = lds + ((t & 1) << 13);

        // -- stage tile t: cvt-once (waits t's own loads), swizzled 8B LDS writes --
        *(short4v*)(lb + dst0) = cvt4(s0);
        *(short4v*)(lb + dst1) = cvt4(s1);
        *(short4v*)(lb + dst2) = cvt4(s2);
        *(short4v*)(lb + dst3) = cvt4(s3);

        // -- hout from regs (before s-regs are overwritten); never drained by barrier --
        if (do_hout) {
            *(f32x4*)(op)      = s0;
            *(f32x4*)(op + 4)  = s1;
            *(f32x4*)(op + 8)  = s2;
            *(f32x4*)(op + 12) = s3;
            op += 2048;
        }

        // -- prefetch t+1 BEFORE the barrier: loads cross it, full-tile latency cover --
        if (t + 1 < t1) {
            gp += 2048;
            s0 = *(const f32x4*)(gp);
            s1 = *(const f32x4*)(gp + 4);
            s2 = *(const f32x4*)(gp + 8);
            s3 = *(const f32x4*)(gp + 12);
        }

        // -- LDS-only barrier: no vmcnt(0) drain (the r4/r5 per-tile stall) --
        LDS_BARRIER();

        // -- compute tile t --
        f32x4 hv = *(const f32x4*)hvp;                  // L1-hit (staged by this block)
        short8 xa[4], ha[4];
        #pragma unroll
        for (int s = 0; s < 4; ++s) {
            xa[s] = *(const short8*)(lb + xoff[s]);
            ha[s] = *(const short8*)(lb + xoff[s] + 4096);
        }
        f32x4 acc[6];
        #pragma unroll
        for (int g = 0; g < 6; ++g) acc[g] = (f32x4){0.f, 0.f, 0.f, 0.f};
        #pragma unroll
        for (int s = 0; s < 4; ++s) {
            #pragma unroll
            for (int g = 0; g < 6; ++g) {
                acc[g] = __builtin_amdgcn_mfma_f32_16x16x32_bf16(
                    wf[g][s], (g < 3) ? xa[s] : ha[s], acc[g], 0, 0, 0);
            }
        }

        // -- epilogue: lane = batch row l15, h-cols h0..h0+3 (r = reg idx) --
        f32x4 yv;
        #pragma unroll
        for (int r = 0; r < 4; ++r) {
            float rv = fast_sigmoid(acc[0][r] + acc[3][r] + br4[r]);
            float zv = fast_sigmoid(acc[1][r] + acc[4][r] + bz4[r]);
            float nv = fast_tanh(acc[2][r] + bin4[r] + rv * (acc[5][r] + bhn4[r]));
            yv[r] = (1.0f - zv) * nv + zv * hv[r];
        }
        *(f32x4*)yp = yv;
        hvp += 2048; yp += 2048;

        // -- second barrier NOT needed: next tile writes the OTHER LDS buffer; this
        //    buffer's reads (above) complete before each wave's next LDS_BARRIER. --
    }
}

extern "C" void kernel_launch(void* const* d_in, const int* in_sizes, int n_in,
                              void* d_out, int out_size, void* d_ws, size_t ws_size,
                              hipStream_t stream) {
    const float* x   = (const float*)d_in[0];
    const float* hid = (const float*)d_in[1];
    const float* Wih = (const float*)d_in[2];
    const float* Whh = (const float*)d_in[3];
    const float* bih = (const float*)d_in[4];
    const float* bhh = (const float*)d_in[5];

    const int M = in_sizes[0] / 128;               // T*B = 131072
    float* y    = (float*)d_out;
    float* hout = y + (size_t)M * 128;

    const int ntiles = M / 16;                     // 8192 row-tiles
    int ngroups = 1024;
    if (ngroups > ntiles) ngroups = ntiles;
    const int tpb  = (ntiles + ngroups - 1) / ngroups;   // 8 tiles/block at M=131072
    const int grid = 2 * ngroups;                        // x2 column classes

    gru_kernel<<<grid, 256, 0, stream>>>(x, hid, Wih, Whh, bih, bhh, y, hout, ntiles, tpb);
}

// Round 7
// 261.470 us; speedup vs baseline: 1.1032x; 1.0946x over previous
//
#include <hip/hip_runtime.h>
#include <hip/hip_bf16.h>
#include <stdint.h>

// GRUModel: y[t,b,:] = GRUCell(x[t,b,:], hid[t,b,:]) per (t,b). M = T*B = 131072, H = I = 128.
//
// v7: async global_load_lds ring, counted vmcnt (T3+T4). The r4-r6 invariant (4580 cy/tile,
// ~122 us regardless of structure) is depth-1 reg-staged pipelining: loads in flight only ~25%
// of the time, occupancy pinned ~2 blocks/CU -> latency-bound at 2.2 TB/s. Fix = keep 3 tiles
// of DMA loads permanently outstanding per block:
//   - 4-slot LDS ring (4 x 16KB fp32: x tile 8KB + hid tile 8KB), filled by global_load_lds
//     (linear LDS dest; XOR-swizzle applied on the per-lane GLOBAL source, m173 pattern).
//   - Steady iter: s_waitcnt vmcnt(10) -> s_barrier -> issue L(t+3) -> compute(t).
//     K=10 = stores(3 tiles)x2 + loads(2 tiles)x2 younger than L(t); in-order vmcnt retirement
//     (m135) makes this exact. Head peel K=4,6,8; tail peel K=8,6. vmcnt NEVER drained to 0.
//   - No ds_writes at all (DMA writes LDS): barrier needs no lgkm drain; consumer ds_read
//     deps are register-tracked by the compiler.
//   - hv (blend) and hout both served from the LDS hid tile (exact fp32 round-trip); the
//     global hv read is deleted. Stores = y + hout = 2 per tile per block, uniform.
//   - Consumer: fp32 frag ds_read_b128 pairs (swizzled, <=2-way per 16-lane phase = free),
//     cvt_pk to bf16, weights-as-A MFMA (layout verified r2-r6), rcpf gate epilogue.
//   - 1024 blocks x 256 thr (cls split: 64 h-cols); 64KB LDS -> 2 blocks/CU resident.

typedef __attribute__((ext_vector_type(8))) short short8;    // 8 bf16 = 4 VGPRs
typedef __attribute__((ext_vector_type(4))) float f32x4;

#define WAITV(N) asm volatile("s_waitcnt vmcnt(" #N ")" ::: "memory")
#define BAR() do { asm volatile("" ::: "memory"); \
                   __builtin_amdgcn_s_barrier();  \
                   asm volatile("" ::: "memory"); } while (0)

__device__ __forceinline__ float rcpf(float v) { return __builtin_amdgcn_rcpf(v); }
__device__ __forceinline__ float fast_sigmoid(float v) {
    return rcpf(1.0f + __expf(-v));
}
__device__ __forceinline__ float fast_tanh(float v) {
    return 2.0f * rcpf(1.0f + __expf(-2.0f * v)) - 1.0f;  // inf-safe
}

// fp32 -> bf16 (RNE) via HW cvt; compiler packs pairs into v_cvt_pk_bf16_f32
__device__ __forceinline__ short f2bf(float f) {
    union { __hip_bfloat16 b; short s; } u; u.b = __float2bfloat16(f);
    return u.s;
}
__device__ __forceinline__ short8 pack8(f32x4 a, f32x4 b) {
    short8 r;
    r[0] = f2bf(a[0]); r[1] = f2bf(a[1]); r[2] = f2bf(a[2]); r[3] = f2bf(a[3]);
    r[4] = f2bf(b[0]); r[5] = f2bf(b[1]); r[6] = f2bf(b[2]); r[7] = f2bf(b[3]);
    return r;
}

// issue one tile's 16 global_load_lds (this wave's 4): per-lane global src (pre-swizzled),
// wave-uniform LDS dest base (HW adds lane*16).
#define ISSUE(T) do {                                                           \
    const float* tb_ = opsrc + (size_t)(T) * 2048;                              \
    char*        lb_ = lds + (((T) & 3) * 16384) + ldsbase;                     \
    _Pragma("unroll")                                                           \
    for (int j_ = 0; j_ < 4; ++j_) {                                            \
        __builtin_amdgcn_global_load_lds(                                       \
            (const __attribute__((address_space(1))) void*)(tb_ + soff[j_]),    \
            (__attribute__((address_space(3))) void*)(lb_ + j_ * 1024),         \
            16, 0, 0);                                                          \
    }                                                                           \
} while (0)

// compute one tile from its ring slot: frag reads + cvt + 24 MFMA + epilogue + y/hout stores
#define COMPUTE(T) do {                                                         \
    char* sb_ = lds + (((T) & 3) * 16384);                                      \
    f32x4 acc[6];                                                               \
    _Pragma("unroll")                                                           \
    for (int g_ = 0; g_ < 6; ++g_) acc[g_] = (f32x4){0.f, 0.f, 0.f, 0.f};       \
    _Pragma("unroll")                                                           \
    for (int s_ = 0; s_ < 4; ++s_) {                                            \
        f32x4 x0_ = *(const f32x4*)(sb_ + fro[s_][0]);                          \
        f32x4 x1_ = *(const f32x4*)(sb_ + fro[s_][1]);                          \
        f32x4 h0_ = *(const f32x4*)(sb_ + 8192 + fro[s_][0]);                   \
        f32x4 h1_ = *(const f32x4*)(sb_ + 8192 + fro[s_][1]);                   \
        short8 xa_ = pack8(x0_, x1_);                                           \
        short8 ha_ = pack8(h0_, h1_);                                           \
        acc[0] = __builtin_amdgcn_mfma_f32_16x16x32_bf16(wf[0][s_], xa_, acc[0], 0, 0, 0); \
        acc[1] = __builtin_amdgcn_mfma_f32_16x16x32_bf16(wf[1][s_], xa_, acc[1], 0, 0, 0); \
        acc[2] = __builtin_amdgcn_mfma_f32_16x16x32_bf16(wf[2][s_], xa_, acc[2], 0, 0, 0); \
        acc[3] = __builtin_amdgcn_mfma_f32_16x16x32_bf16(wf[3][s_], ha_, acc[3], 0, 0, 0); \
        acc[4] = __builtin_amdgcn_mfma_f32_16x16x32_bf16(wf[4][s_], ha_, acc[4], 0, 0, 0); \
        acc[5] = __builtin_amdgcn_mfma_f32_16x16x32_bf16(wf[5][s_], ha_, acc[5], 0, 0, 0); \
    }                                                                           \
    f32x4 hv_ = *(const f32x4*)(sb_ + 8192 + hvoff);   /* exact fp32 hid */     \
    f32x4 hc_ = *(const f32x4*)(sb_ + 8192 + hooff);   /* hout chunk */         \
    f32x4 yv_;                                                                  \
    _Pragma("unroll")                                                           \
    for (int r_ = 0; r_ < 4; ++r_) {                                            \
        float rv = fast_sigmoid(acc[0][r_] + acc[3][r_] + br4[r_]);             \
        float zv = fast_sigmoid(acc[1][r_] + acc[4][r_] + bz4[r_]);             \
        float nv = fast_tanh(acc[2][r_] + bin4[r_] + rv * (acc[5][r_] + bhn4[r_])); \
        yv_[r_] = (1.0f - zv) * nv + zv * hv_[r_];                              \
    }                                                                           \
    *(f32x4*)(y    + (size_t)(T) * 2048 + yoff)    = yv_;                       \
    *(f32x4*)(hout + (size_t)(T) * 2048 + hooff_g) = hc_;                       \
} while (0)

__global__ __launch_bounds__(256) void gru_kernel(
    const float* __restrict__ x,
    const float* __restrict__ hid,
    const float* __restrict__ Wih,
    const float* __restrict__ Whh,
    const float* __restrict__ bih,
    const float* __restrict__ bhh,
    float* __restrict__ y,
    float* __restrict__ hout,
    int ntiles, int tpb)
{
    // ring: 4 slots x [x fp32 16x128 (8KB) | hid fp32 16x128 (8KB)]; rows 512B,
    // 16B-chunk swizzle cc^(row&7) applied on global src + all LDS reads.
    __shared__ __align__(16) char lds[4 * 16384];    // 64 KB

    const int tid  = threadIdx.x;
    const int lane = tid & 63;
    const int w    = tid >> 6;       // wave 0..3
    const int l15  = lane & 15;
    const int q    = lane >> 4;      // quad 0..3

    const int cls = blockIdx.x & 1;          // h-cols cls*64 .. cls*64+63
    const int grp = blockIdx.x >> 1;

    const int t0 = grp * tpb;
    const int t1 = (t0 + tpb < ntiles) ? (t0 + tpb) : ntiles;
    if (t0 >= t1) return;
    const int nt = t1 - t0;

    // ---- weights -> VGPR A-fragments (L2/L3-resident source; layout verified r2-r6) ----
    short8 wf[6][4];                 // g = {i_r,i_z,i_n,h_r,h_z,h_n}
    #pragma unroll
    for (int g = 0; g < 6; ++g) {
        const float* Wp  = (g < 3) ? Wih : Whh;
        const float* src = Wp + (size_t)((g % 3) * 128 + cls * 64 + w * 16 + l15) * 128 + q * 8;
        #pragma unroll
        for (int s = 0; s < 4; ++s) {
            f32x4 a = *(const f32x4*)(src + s * 32);
            f32x4 b = *(const f32x4*)(src + s * 32 + 4);
            wf[g][s] = pack8(a, b);
        }
    }

    // ---- per-lane biases for this lane's 4 h-cols ----
    const int h0 = cls * 64 + w * 16 + q * 4;
    f32x4 br4  = *(const f32x4*)(bih + h0)       + *(const f32x4*)(bhh + h0);
    f32x4 bz4  = *(const f32x4*)(bih + 128 + h0) + *(const f32x4*)(bhh + 128 + h0);
    f32x4 bin4 = *(const f32x4*)(bih + 256 + h0);
    f32x4 bhn4 = *(const f32x4*)(bhh + 256 + h0);

    // ---- producer geometry: wave w -> operand w>>1 (0=x,1=hid), row-pairs (w&1)*4.. ----
    const float* opsrc  = (w < 2) ? x : hid;
    const int    pair0  = (w & 1) * 4;
    const unsigned ldsbase = (unsigned)(w >> 1) * 8192u + (unsigned)pair0 * 1024u;
    int soff[4];                     // per-lane pre-swizzled global float offsets
    #pragma unroll
    for (int j = 0; j < 4; ++j) {
        int row = 2 * (pair0 + j) + (lane >> 5);
        int ccg = (lane & 31) ^ (row & 7);
        soff[j] = row * 128 + ccg * 4;
    }

    // ---- consumer offsets (all swizzled to match) ----
    int fro[4][2];                   // fragment reads: row l15, chunks s*8+q*2 (+1)
    #pragma unroll
    for (int s = 0; s < 4; ++s) {
        #pragma unroll
        for (int hhi = 0; hhi < 2; ++hhi) {
            int cc = s * 8 + q * 2 + hhi;
            fro[s][hhi] = l15 * 512 + ((cc ^ (l15 & 7)) * 16);
        }
    }
    const int hvoff = l15 * 512 + ((((cls * 16) + w * 4 + q) ^ (l15 & 7)) * 16);

    // hout: this block stores rows cls*8..cls*8+7 (half tile); lane -> chunk oc
    const int oc     = cls * 256 + tid;
    const int row_o  = oc >> 5;
    const int cc_o   = oc & 31;
    const int hooff  = row_o * 512 + ((cc_o ^ (row_o & 7)) * 16);   // LDS byte
    const int hooff_g = row_o * 128 + cc_o * 4;                     // global float
    const int yoff    = l15 * 128 + h0;                             // global float

    if (nt >= 6) {
        ISSUE(t0); ISSUE(t0 + 1); ISSUE(t0 + 2);
        // head peel: K = #vmem ops younger than L(t) at each wait (in-order retirement)
        WAITV(4);  BAR(); ISSUE(t0 + 3); COMPUTE(t0);
        WAITV(6);  BAR(); ISSUE(t0 + 4); COMPUTE(t0 + 1);
        WAITV(8);  BAR(); ISSUE(t0 + 5); COMPUTE(t0 + 2);
        for (int t = t0 + 3; t < t1 - 3; ++t) {
            WAITV(10); BAR(); ISSUE(t + 3); COMPUTE(t);
        }
        WAITV(10); BAR(); COMPUTE(t1 - 3);
        WAITV(8);  BAR(); COMPUTE(t1 - 2);
        WAITV(6);  BAR(); COMPUTE(t1 - 1);
    } else {
        // small-tail fallback (not hit at M=131072)
        for (int t = t0; t < t1; ++t) {
            ISSUE(t); WAITV(0); BAR(); COMPUTE(t);
        }
    }
}

extern "C" void kernel_launch(void* const* d_in, const int* in_sizes, int n_in,
                              void* d_out, int out_size, void* d_ws, size_t ws_size,
                              hipStream_t stream) {
    const float* x   = (const float*)d_in[0];
    const float* hid = (const float*)d_in[1];
    const float* Wih = (const float*)d_in[2];
    const float* Whh = (const float*)d_in[3];
    const float* bih = (const float*)d_in[4];
    const float* bhh = (const float*)d_in[5];

    const int M = in_sizes[0] / 128;               // T*B = 131072
    float* y    = (float*)d_out;
    float* hout = y + (size_t)M * 128;

    const int ntiles = M / 16;                     // 8192 row-tiles
    const int tpb    = 16;
    const int ngroups = (ntiles + tpb - 1) / tpb;  // 512
    const int grid    = 2 * ngroups;               // x2 column classes -> 1024 blocks

    gru_kernel<<<grid, 256, 0, stream>>>(x, hid, Wih, Whh, bih, bhh, y, hout, ntiles, tpb);
}